// Round 2
// baseline (2188.430 us; speedup 1.0000x reference)
//
#include <hip/hip_runtime.h>

// ---------------------------------------------------------------------------
// SlotAttention on MI355X (gfx950) — single persistent kernel, software grid
// barrier (NO cooperative launch: round-1 evidence says coop API under graph
// capture is the failure point). 256 blocks x 256 threads: 1 block/CU needs
// only occupancy>=1 -> spin barrier is deadlock-proof for ANY reg/LDS alloc.
// Phases (7 software grid barriers):
//   P0: weight->bf16 + slots init + LN(inputs)->bf16
//   P1: kv GEMM (1024 tiles, 4/block) + init q (blocks 0..15)
//   3x { ATTN (256 blocks: 32 b x 8 chunks of 128 tokens) ; ROW (16 blocks,
//        16 slot-rows each: combine+GRU+LN+MLP+residual+LN+next-q) }
// MFMA fragment layouts per learn_hip m89/m97 (ref-verified):
//   A/B operand: idx = lane&15 (m or n), k = (lane>>4)*8 + j
//   C/D:         col = lane&15, row = (lane>>4)*4 + reg
// ---------------------------------------------------------------------------

typedef __attribute__((ext_vector_type(8))) __bf16 bf16x8;
typedef __attribute__((ext_vector_type(4))) float  f32x4;

#define MFMA16(a, b, c) __builtin_amdgcn_mfma_f32_16x16x32_bf16((a), (b), (c), 0, 0, 0)

static __device__ __forceinline__ unsigned short f2bf(float f) {
    unsigned int x = __float_as_uint(f);
    x = (x + 0x7fffu + ((x >> 16) & 1u)) >> 16;   // RN-even
    return (unsigned short)x;
}

struct Params {
    const float *inputs, *noise, *mu, *ls;
    const float *Wq, *Wk, *Wv, *wih, *whh, *bih, *bhh, *w1, *b1, *w2, *b2;
    const float *ln_in_g, *ln_in_b, *ln_s_g, *ln_s_b, *ln_ff_g, *ln_ff_b;
    float* out;
    unsigned*  bar;   // grid barrier counter (memset to 0 before launch)
    unsigned short *x_bf, *kvW_bf, *Wq_bf, *wih_bf, *whh_bf, *w1_bf, *w2_bf;
    float *kv, *slots, *q, *upart, *rspart;
};

union Smem {
    struct { unsigned short As[128 * 32], Bs[128 * 32]; } g;          // 16 KB (kv gemm)
    struct { float q[8][260]; float sc[8][132]; } at;                 // 12.3 KB (attn)
    struct {
        unsigned short u[16][264];     // combine result / ln_s (bf16, pad +8)
        unsigned short h[16][264];     // slots_prev bf16
        unsigned short ff[16][264];    // LN_ff out bf16
        unsigned short h1[16][520];    // half of MLP hidden (512 + 8 pad)
        float          s[16][260];     // slots f32 (prev -> mid -> new)
    } row;                                                             // 57.25 KB
};

// ---- software grid barrier: monotonic counter, per-phase target -------------
// __syncthreads drains each wave's vmem (vmcnt(0) before s_barrier); leader's
// agent-scope ACQ_REL RMW writes back / invalidates caches for cross-XCD
// visibility; acquire spin-load + trailing __syncthreads publish to the block.
static __device__ __forceinline__ void gridbar(unsigned* bar, unsigned target) {
    __syncthreads();
    if (threadIdx.x == 0) {
        __hip_atomic_fetch_add(bar, 1u, __ATOMIC_ACQ_REL, __HIP_MEMORY_SCOPE_AGENT);
        while (__hip_atomic_load(bar, __ATOMIC_ACQUIRE, __HIP_MEMORY_SCOPE_AGENT) < target)
            __builtin_amdgcn_s_sleep(1);
    }
    __syncthreads();
}

// ---------------- P0b: LN(inputs) rows -> bf16, one row per wave ------------
static __device__ void ln_input(const Params& p) {
    const int wid  = (blockIdx.x * 256 + threadIdx.x) >> 6;   // 0..1023
    const int lane = threadIdx.x & 63;
    const float g0 = p.ln_in_g[lane * 4 + 0], g1 = p.ln_in_g[lane * 4 + 1];
    const float g2 = p.ln_in_g[lane * 4 + 2], g3 = p.ln_in_g[lane * 4 + 3];
    const float b0 = p.ln_in_b[lane * 4 + 0], b1 = p.ln_in_b[lane * 4 + 1];
    const float b2 = p.ln_in_b[lane * 4 + 2], b3 = p.ln_in_b[lane * 4 + 3];
    #pragma unroll 2
    for (int row = wid; row < 32768; row += 1024) {
        float4 v = *(const float4*)(p.inputs + (size_t)row * 256 + lane * 4);
        float s  = v.x + v.y + v.z + v.w;
        float ss = v.x * v.x + v.y * v.y + v.z * v.z + v.w * v.w;
        #pragma unroll
        for (int o = 1; o < 64; o <<= 1) { s += __shfl_xor(s, o); ss += __shfl_xor(ss, o); }
        float mean = s * (1.f / 256.f);
        float var  = ss * (1.f / 256.f) - mean * mean;
        float rstd = rsqrtf(var + 1e-5f);
        ushort4 o4;
        o4.x = f2bf((v.x - mean) * rstd * g0 + b0);
        o4.y = f2bf((v.y - mean) * rstd * g1 + b1);
        o4.z = f2bf((v.z - mean) * rstd * g2 + b2);
        o4.w = f2bf((v.w - mean) * rstd * g3 + b3);
        *(ushort4*)(p.x_bf + (size_t)row * 256 + lane * 4) = o4;
    }
}

// ---------------- P1a: kv = x_ln @ [Wk;Wv]^T, one 128x128 tile --------------
static __device__ void kv_tile(const Params& p, Smem& sm, int tile) {
    const int m0 = (tile >> 2) * 128, n0 = (tile & 3) * 128;
    const int t = threadIdx.x, wave = t >> 6, lane = t & 63;
    const int qr = (wave >> 1) * 64, qc = (wave & 1) * 64;
    const int lr = lane & 15, lq = lane >> 4;
    f32x4 acc[4][4] = {};
    const int sr = t >> 2, sc = (t & 3) * 8;
    for (int k0 = 0; k0 < 256; k0 += 32) {
        __syncthreads();
        uint4 a0 = *(const uint4*)(p.x_bf   + (size_t)(m0 + sr)      * 256 + k0 + sc);
        uint4 a1 = *(const uint4*)(p.x_bf   + (size_t)(m0 + sr + 64) * 256 + k0 + sc);
        uint4 b0 = *(const uint4*)(p.kvW_bf + (size_t)(n0 + sr)      * 256 + k0 + sc);
        uint4 b1 = *(const uint4*)(p.kvW_bf + (size_t)(n0 + sr + 64) * 256 + k0 + sc);
        *(uint4*)(sm.g.As + sr * 32 + sc) = a0;
        *(uint4*)(sm.g.As + (sr + 64) * 32 + sc) = a1;
        *(uint4*)(sm.g.Bs + sr * 32 + sc) = b0;
        *(uint4*)(sm.g.Bs + (sr + 64) * 32 + sc) = b1;
        __syncthreads();
        bf16x8 af[4], bv[4];
        #pragma unroll
        for (int i = 0; i < 4; i++) af[i] = *(const bf16x8*)(sm.g.As + (qr + i * 16 + lr) * 32 + lq * 8);
        #pragma unroll
        for (int i = 0; i < 4; i++) bv[i] = *(const bf16x8*)(sm.g.Bs + (qc + i * 16 + lr) * 32 + lq * 8);
        #pragma unroll
        for (int i = 0; i < 4; i++)
            #pragma unroll
            for (int j = 0; j < 4; j++)
                acc[i][j] = MFMA16(af[i], bv[j], acc[i][j]);
    }
    #pragma unroll
    for (int i = 0; i < 4; i++)
        #pragma unroll
        for (int j = 0; j < 4; j++) {
            const int col = n0 + qc + j * 16 + lr;
            #pragma unroll
            for (int r = 0; r < 4; r++) {
                const int rw = m0 + qr + i * 16 + lq * 4 + r;
                p.kv[(size_t)rw * 512 + col] = acc[i][j][r];
            }
        }
}

// ---------------- q = ln_s(16 rows in sm.row.u) @ Wq^T ----------------------
static __device__ void qgemm(const Params& p, Smem& sm, int r0) {
    const int t = threadIdx.x, w = t >> 6, lane = t & 63;
    const int lr = lane & 15, lq = lane >> 4;
    f32x4 acc[4] = {};
    for (int k0 = 0; k0 < 256; k0 += 32) {
        bf16x8 a = *(const bf16x8*)&sm.row.u[lr][k0 + lq * 8];
        #pragma unroll
        for (int j = 0; j < 4; ++j) {
            bf16x8 bv = *(const bf16x8*)(p.Wq_bf + (size_t)(w * 64 + j * 16 + lr) * 256 + k0 + lq * 8);
            acc[j] = MFMA16(a, bv, acc[j]);
        }
    }
    #pragma unroll
    for (int j = 0; j < 4; ++j)
        #pragma unroll
        for (int r = 0; r < 4; ++r)
            p.q[(size_t)(r0 + lq * 4 + r) * 256 + w * 64 + j * 16 + lr] = acc[j][r];
}

// ---------------- P1b: initial LN(slots) -> q (blocks 0..15) ----------------
static __device__ void init_q(const Params& p, Smem& sm, int bid) {
    const int t = threadIdx.x;
    const int r0 = bid * 16;
    const int row16 = t >> 4, sub = t & 15;
    float vals[16]; float s = 0.f, ss = 0.f;
    #pragma unroll
    for (int k = 0; k < 16; k += 4) {
        float4 v = *(const float4*)(p.slots + (size_t)(r0 + row16) * 256 + sub * 16 + k);
        vals[k] = v.x; vals[k + 1] = v.y; vals[k + 2] = v.z; vals[k + 3] = v.w;
        s += v.x + v.y + v.z + v.w;
        ss += v.x * v.x + v.y * v.y + v.z * v.z + v.w * v.w;
    }
    #pragma unroll
    for (int m = 1; m < 16; m <<= 1) { s += __shfl_xor(s, m); ss += __shfl_xor(ss, m); }
    const float mean = s * (1.f / 256.f);
    const float var  = ss * (1.f / 256.f) - mean * mean;
    const float rstd = rsqrtf(var + 1e-5f);
    #pragma unroll
    for (int k = 0; k < 16; ++k) {
        const int c = sub * 16 + k;
        sm.row.u[row16][c] = f2bf((vals[k] - mean) * rstd * p.ln_s_g[c] + p.ln_s_b[c]);
    }
    __syncthreads();
    qgemm(p, sm, r0);
}

// ---------------- ATTN: dots + softmax(slots) + EPS + partial sums ----------
// 256 blocks: b = bid>>3 (32 batches), chunk = bid&7 (8 chunks of 128 tokens).
static __device__ void attn_phase(const Params& p, Smem& sm, int bid) {
    const int t = threadIdx.x;
    const int b = bid >> 3, chunk = bid & 7, j0 = chunk * 128;
    {   // q rows for this batch (8 x 256 f32)
        const int i = t >> 5, c0 = (t & 31) * 8;
        const float* qr = p.q + (size_t)(b * 8 + i) * 256 + c0;
        *(float4*)&sm.at.q[i][c0]     = *(const float4*)(qr);
        *(float4*)&sm.at.q[i][c0 + 4] = *(const float4*)(qr + 4);
    }
    __syncthreads();
    {   // dots for 128 tokens x 8 slots
        const int i = t & 7, jj = t >> 3;
        const float4* qrow = (const float4*)&sm.at.q[i][0];
        #pragma unroll 1
        for (int g = 0; g < 4; ++g) {
            const int jl = g * 32 + jj;
            const float4* krow = (const float4*)(p.kv + ((size_t)b * 1024 + j0 + jl) * 512);
            float a0 = 0, a1 = 0, a2 = 0, a3 = 0;
            #pragma unroll 8
            for (int dd = 0; dd < 64; ++dd) {
                float4 qv = qrow[dd], kk = krow[dd];
                a0 += qv.x * kk.x; a1 += qv.y * kk.y; a2 += qv.z * kk.z; a3 += qv.w * kk.w;
            }
            sm.at.sc[i][jl] = (a0 + a1 + a2 + a3) * 0.0625f;   // SCALE
        }
    }
    __syncthreads();
    if (t < 128) {  // softmax over slots per token + EPS
        float v[8], m = -1e30f;
        #pragma unroll
        for (int ii = 0; ii < 8; ++ii) { v[ii] = sm.at.sc[ii][t]; m = fmaxf(m, v[ii]); }
        float s = 0.f;
        #pragma unroll
        for (int ii = 0; ii < 8; ++ii) { v[ii] = __expf(v[ii] - m); s += v[ii]; }
        const float inv = 1.f / s;
        #pragma unroll
        for (int ii = 0; ii < 8; ++ii) sm.at.sc[ii][t] = v[ii] * inv + 1e-8f;
    }
    __syncthreads();
    if (t < 8) {    // per-slot row-sum partial
        float s = 0.f;
        for (int jl = 0; jl < 128; ++jl) s += sm.at.sc[t][jl];
        p.rspart[((size_t)b * 8 + chunk) * 8 + t] = s;
    }
    {   // partial updates: acc[i] += w[i][j] * v[j][d], d = t
        float acc[8] = {};
        const float* vbase = p.kv + ((size_t)b * 1024 + j0) * 512 + 256 + t;
        for (int jl = 0; jl < 128; ++jl) {
            const float vv = vbase[(size_t)jl * 512];
            #pragma unroll
            for (int ii = 0; ii < 8; ++ii) acc[ii] += sm.at.sc[ii][jl] * vv;
        }
        float* up = p.upart + (((size_t)b * 8 + chunk) * 8) * 256 + t;
        #pragma unroll
        for (int ii = 0; ii < 8; ++ii) up[(size_t)ii * 256] = acc[ii];
    }
}

// ---------------- ROW: combine -> gates -> GRU -> LN -> MLP -> out -> q -----
static __device__ void row_phase(const Params& p, Smem& sm, int bid, int it) {
    const int t = threadIdx.x;
    const int r0 = bid * 16;
    const int lane = t & 63, w = t >> 6;
    const int lr = lane & 15, lq = lane >> 4;
    const int row16 = t >> 4, sub = t & 15;
    const int c0 = w * 64;

    // 1. slots f32 -> s LDS (+ bf16 h LDS); combine upart/rspart -> u LDS bf16
    #pragma unroll
    for (int k = 0; k < 16; k += 4) {
        float4 v = *(const float4*)(p.slots + (size_t)(r0 + row16) * 256 + sub * 16 + k);
        *(float4*)&sm.row.s[row16][sub * 16 + k] = v;
        sm.row.h[row16][sub * 16 + k]     = f2bf(v.x);
        sm.row.h[row16][sub * 16 + k + 1] = f2bf(v.y);
        sm.row.h[row16][sub * 16 + k + 2] = f2bf(v.z);
        sm.row.h[row16][sub * 16 + k + 3] = f2bf(v.w);
    }
    {
        const int grow = r0 + row16, bb = grow >> 3, ii = grow & 7;
        float rs = 0.f;
        #pragma unroll
        for (int c = 0; c < 8; ++c) rs += p.rspart[((size_t)bb * 8 + c) * 8 + ii];
        const float inv = 1.f / rs;
        float uac[16] = {};
        #pragma unroll
        for (int c = 0; c < 8; ++c) {
            const float* up = p.upart + (((size_t)bb * 8 + c) * 8 + ii) * 256 + sub * 16;
            #pragma unroll
            for (int k = 0; k < 16; k += 4) {
                float4 v = *(const float4*)(up + k);
                uac[k] += v.x; uac[k + 1] += v.y; uac[k + 2] += v.z; uac[k + 3] += v.w;
            }
        }
        #pragma unroll
        for (int k = 0; k < 16; ++k) sm.row.u[row16][sub * 16 + k] = f2bf(uac[k] * inv);
    }
    __syncthreads();

    // 2. GRU gates: wave w owns output cols c0..c0+63; computes gi/gh for all
    //    three col-thirds so the GRU is lane-local (C-layout tiles j, j+16, j+32).
    f32x4 gi[3][4] = {}, gh[3][4] = {};
    for (int k0 = 0; k0 < 256; k0 += 32) {
        bf16x8 au = *(const bf16x8*)&sm.row.u[lr][k0 + lq * 8];
        bf16x8 ah = *(const bf16x8*)&sm.row.h[lr][k0 + lq * 8];
        #pragma unroll
        for (int tau = 0; tau < 3; ++tau)
            #pragma unroll
            for (int j = 0; j < 4; ++j) {
                const size_t boff = (size_t)(tau * 256 + c0 + j * 16 + lr) * 256 + k0 + lq * 8;
                gi[tau][j] = MFMA16(au, *(const bf16x8*)(p.wih_bf + boff), gi[tau][j]);
                gh[tau][j] = MFMA16(ah, *(const bf16x8*)(p.whh_bf + boff), gh[tau][j]);
            }
    }

    // 3. GRU elementwise (lane-local), overwrite s with slots_mid
    #pragma unroll
    for (int j = 0; j < 4; ++j) {
        const int c = c0 + j * 16 + lr;
        const float bir = p.bih[c], biz = p.bih[256 + c], bin_ = p.bih[512 + c];
        const float bhr = p.bhh[c], bhz = p.bhh[256 + c], bhn  = p.bhh[512 + c];
        #pragma unroll
        for (int r = 0; r < 4; ++r) {
            const int rw = lq * 4 + r;
            const float rg = 1.f / (1.f + __expf(-(gi[0][j][r] + bir + gh[0][j][r] + bhr)));
            const float z  = 1.f / (1.f + __expf(-(gi[1][j][r] + biz + gh[1][j][r] + bhz)));
            const float nn = tanhf(gi[2][j][r] + bin_ + rg * (gh[2][j][r] + bhn));
            const float h  = sm.row.s[rw][c];
            sm.row.s[rw][c] = (1.f - z) * nn + z * h;
        }
    }
    __syncthreads();

    // 4. LN_ff -> ff LDS bf16
    {
        float vals[16]; float s_ = 0.f, ss = 0.f;
        #pragma unroll
        for (int k = 0; k < 16; ++k) {
            const float v = sm.row.s[row16][sub * 16 + k];
            vals[k] = v; s_ += v; ss += v * v;
        }
        #pragma unroll
        for (int m = 1; m < 16; m <<= 1) { s_ += __shfl_xor(s_, m); ss += __shfl_xor(ss, m); }
        const float mean = s_ * (1.f / 256.f);
        const float var  = ss * (1.f / 256.f) - mean * mean;
        const float rstd = rsqrtf(var + 1e-5f);
        #pragma unroll
        for (int k = 0; k < 16; ++k) {
            const int c = sub * 16 + k;
            sm.row.ff[row16][c] = f2bf((vals[k] - mean) * rstd * p.ln_ff_g[c] + p.ln_ff_b[c]);
        }
    }
    __syncthreads();

    // 5. MLP: h1 = relu(ff @ w1^T + b1) in 2 halves; out-acc += h1 @ w2^T slice
    f32x4 oacc[4] = {};
    #pragma unroll 1
    for (int half = 0; half < 2; ++half) {
        f32x4 hacc[8] = {};
        for (int k0 = 0; k0 < 256; k0 += 32) {
            bf16x8 af = *(const bf16x8*)&sm.row.ff[lr][k0 + lq * 8];
            #pragma unroll
            for (int j = 0; j < 8; ++j) {
                bf16x8 bv = *(const bf16x8*)(p.w1_bf + (size_t)(half * 512 + w * 128 + j * 16 + lr) * 256 + k0 + lq * 8);
                hacc[j] = MFMA16(af, bv, hacc[j]);
            }
        }
        #pragma unroll
        for (int j = 0; j < 8; ++j) {
            const int cl = w * 128 + j * 16 + lr;
            const float bb = p.b1[half * 512 + cl];
            #pragma unroll
            for (int r = 0; r < 4; ++r)
                sm.row.h1[lq * 4 + r][cl] = f2bf(fmaxf(hacc[j][r] + bb, 0.f));
        }
        __syncthreads();
        for (int k0 = 0; k0 < 512; k0 += 32) {
            bf16x8 a1 = *(const bf16x8*)&sm.row.h1[lr][k0 + lq * 8];
            #pragma unroll
            for (int j = 0; j < 4; ++j) {
                bf16x8 bv = *(const bf16x8*)(p.w2_bf + (size_t)(c0 + j * 16 + lr) * 1024 + half * 512 + k0 + lq * 8);
                oacc[j] = MFMA16(a1, bv, oacc[j]);
            }
        }
        __syncthreads();
    }

    // 6. out = mlp + b2 + slots_mid; write slots (and d_out on last iter)
    const bool last = (it == 2);
    #pragma unroll
    for (int j = 0; j < 4; ++j) {
        const int c = c0 + j * 16 + lr;
        const float bb = p.b2[c];
        #pragma unroll
        for (int r = 0; r < 4; ++r) {
            const int rw = lq * 4 + r;
            const float val = oacc[j][r] + bb + sm.row.s[rw][c];
            sm.row.s[rw][c] = val;
            p.slots[(size_t)(r0 + rw) * 256 + c] = val;
            if (last) p.out[(size_t)(r0 + rw) * 256 + c] = val;
        }
    }
    if (last) return;
    __syncthreads();

    // 7. LN(slots_new) -> u LDS; q for next iteration
    {
        float vals[16]; float s_ = 0.f, ss = 0.f;
        #pragma unroll
        for (int k = 0; k < 16; ++k) {
            const float v = sm.row.s[row16][sub * 16 + k];
            vals[k] = v; s_ += v; ss += v * v;
        }
        #pragma unroll
        for (int m = 1; m < 16; m <<= 1) { s_ += __shfl_xor(s_, m); ss += __shfl_xor(ss, m); }
        const float mean = s_ * (1.f / 256.f);
        const float var  = ss * (1.f / 256.f) - mean * mean;
        const float rstd = rsqrtf(var + 1e-5f);
        #pragma unroll
        for (int k = 0; k < 16; ++k) {
            const int c = sub * 16 + k;
            sm.row.u[row16][c] = f2bf((vals[k] - mean) * rstd * p.ln_s_g[c] + p.ln_s_b[c]);
        }
    }
    __syncthreads();
    qgemm(p, sm, r0);
}

// ---------------------------------------------------------------------------
__global__ __launch_bounds__(256) void fused(Params p) {
    __shared__ Smem sm;
    const int bid = blockIdx.x, t = threadIdx.x;
    unsigned target = 0;

    // ---- P0: weights -> bf16, slots init, LN(inputs) -> bf16
    for (int gid = bid * 256 + t; gid < 1179648; gid += 65536) {
        if      (gid <   65536) p.kvW_bf[gid]          = f2bf(p.Wk[gid]);
        else if (gid <  131072) p.kvW_bf[gid]          = f2bf(p.Wv[gid -   65536]);
        else if (gid <  196608) p.Wq_bf[gid - 131072]  = f2bf(p.Wq[gid -  131072]);
        else if (gid <  393216) p.wih_bf[gid - 196608] = f2bf(p.wih[gid - 196608]);
        else if (gid <  589824) p.whh_bf[gid - 393216] = f2bf(p.whh[gid - 393216]);
        else if (gid <  851968) p.w1_bf[gid - 589824]  = f2bf(p.w1[gid -  589824]);
        else if (gid < 1114112) p.w2_bf[gid - 851968]  = f2bf(p.w2[gid -  851968]);
        else {
            const int i = gid - 1114112;
            const int d = i & 255;
            p.slots[i] = p.mu[d] + expf(p.ls[d]) * p.noise[i];
        }
    }
    ln_input(p);
    gridbar(p.bar, target += 256);

    // ---- P1: kv GEMM (1024 tiles, 4/block) + initial q (blocks 0..15)
    for (int tt = bid; tt < 1024; tt += 256) kv_tile(p, sm, tt);
    if (bid < 16) { __syncthreads(); init_q(p, sm, bid); }
    gridbar(p.bar, target += 256);

    // ---- 3 slot-attention iterations
    for (int it = 0; it < 3; ++it) {
        attn_phase(p, sm, bid);
        gridbar(p.bar, target += 256);
        if (bid < 16) row_phase(p, sm, bid, it);
        if (it < 2) gridbar(p.bar, target += 256);
    }
}

// ---------------------------------------------------------------------------
extern "C" void kernel_launch(void* const* d_in, const int* in_sizes, int n_in,
                              void* d_out, int out_size, void* d_ws, size_t ws_size,
                              hipStream_t stream)
{
    (void)in_sizes; (void)n_in; (void)out_size; (void)ws_size;

    Params prm;
    prm.inputs  = (const float*)d_in[0];
    prm.noise   = (const float*)d_in[1];
    prm.mu      = (const float*)d_in[2];
    prm.ls      = (const float*)d_in[3];
    prm.Wq      = (const float*)d_in[4];
    prm.Wk      = (const float*)d_in[5];
    prm.Wv      = (const float*)d_in[6];
    prm.wih     = (const float*)d_in[7];
    prm.whh     = (const float*)d_in[8];
    prm.bih     = (const float*)d_in[9];
    prm.bhh     = (const float*)d_in[10];
    prm.w1      = (const float*)d_in[11];
    prm.b1      = (const float*)d_in[12];
    prm.w2      = (const float*)d_in[13];
    prm.b2      = (const float*)d_in[14];
    prm.ln_in_g = (const float*)d_in[15];
    prm.ln_in_b = (const float*)d_in[16];
    prm.ln_s_g  = (const float*)d_in[17];
    prm.ln_s_b  = (const float*)d_in[18];
    prm.ln_ff_g = (const float*)d_in[19];
    prm.ln_ff_b = (const float*)d_in[20];
    prm.out     = (float*)d_out;

    char* ptr = (char*)d_ws;
    auto alloc = [&](size_t bytes) -> char* {
        char* r = ptr; ptr += (bytes + 255) & ~(size_t)255; return r;
    };
    prm.bar    = (unsigned*)      alloc(256);
    prm.x_bf   = (unsigned short*)alloc((size_t)32768 * 256 * 2);
    prm.kv     = (float*)         alloc((size_t)32768 * 512 * 4);
    prm.kvW_bf = (unsigned short*)alloc(512 * 256 * 2);
    prm.Wq_bf  = (unsigned short*)alloc(256 * 256 * 2);
    prm.wih_bf = (unsigned short*)alloc(768 * 256 * 2);
    prm.whh_bf = (unsigned short*)alloc(768 * 256 * 2);
    prm.w1_bf  = (unsigned short*)alloc(1024 * 256 * 2);
    prm.w2_bf  = (unsigned short*)alloc(256 * 1024 * 2);
    prm.slots  = (float*)         alloc(256 * 256 * 4);
    prm.q      = (float*)         alloc(256 * 256 * 4);
    prm.upart  = (float*)         alloc((size_t)32 * 8 * 8 * 256 * 4);
    prm.rspart = (float*)         alloc(32 * 8 * 8 * 4);

    hipMemsetAsync(prm.bar, 0, 256, stream);
    fused<<<dim3(256), dim3(256), 0, stream>>>(prm);
}

// Round 3
// 753.277 us; speedup vs baseline: 2.9052x; 2.9052x over previous
//
#include <hip/hip_runtime.h>

// ---------------------------------------------------------------------------
// SlotAttention on MI355X (gfx950) — single persistent kernel, software grid
// barrier. 256 blocks x 256 threads: 1 block/CU -> spin barrier deadlock-proof.
// Round-2 lesson: ACQUIRE polling + ACQ_REL RMW at agent scope emit cache
// writeback/invalidate PER POLL -> ~300us per barrier, machine 99% idle.
// Fix: release-RMW once, RELAXED polls, ONE acquire fence on exit.
// Phases (7 software grid barriers):
//   P0: weight->bf16 + slots init + LN(inputs)->bf16
//   P1: kv GEMM (1024 tiles, 4/block) + init q (blocks 0..15)
//   3x { ATTN (256 blocks: 32 b x 8 chunks of 128 tokens) ; ROW (16 blocks,
//        16 slot-rows each: combine+GRU+LN+MLP+residual+LN+next-q) }
// MFMA fragment layouts per learn_hip m89/m97 (ref-verified):
//   A/B operand: idx = lane&15 (m or n), k = (lane>>4)*8 + j
//   C/D:         col = lane&15, row = (lane>>4)*4 + reg
// kv-GEMM LDS tiles XOR-swizzled (slot ^= (row>>1)&3): read conflicts 8->2 way.
// ---------------------------------------------------------------------------

typedef __attribute__((ext_vector_type(8))) __bf16 bf16x8;
typedef __attribute__((ext_vector_type(4))) float  f32x4;

#define MFMA16(a, b, c) __builtin_amdgcn_mfma_f32_16x16x32_bf16((a), (b), (c), 0, 0, 0)

static __device__ __forceinline__ unsigned short f2bf(float f) {
    unsigned int x = __float_as_uint(f);
    x = (x + 0x7fffu + ((x >> 16) & 1u)) >> 16;   // RN-even
    return (unsigned short)x;
}

struct Params {
    const float *inputs, *noise, *mu, *ls;
    const float *Wq, *Wk, *Wv, *wih, *whh, *bih, *bhh, *w1, *b1, *w2, *b2;
    const float *ln_in_g, *ln_in_b, *ln_s_g, *ln_s_b, *ln_ff_g, *ln_ff_b;
    float* out;
    unsigned*  bar;   // grid barrier counter (memset to 0 before launch)
    unsigned short *x_bf, *kvW_bf, *Wq_bf, *wih_bf, *whh_bf, *w1_bf, *w2_bf;
    float *kv, *slots, *q, *upart, *rspart;
};

union Smem {
    struct { unsigned short As[128 * 32], Bs[128 * 32]; } g;          // 16 KB (kv gemm)
    struct { float q[8][260]; float sc[8][132]; } at;                 // 12.3 KB (attn)
    struct {
        unsigned short u[16][264];     // combine result / ln_s (bf16, pad +8)
        unsigned short h[16][264];     // slots_prev bf16
        unsigned short ff[16][264];    // LN_ff out bf16
        unsigned short h1[16][520];    // half of MLP hidden (512 + 8 pad)
        float          s[16][260];     // slots f32 (prev -> mid -> new)
    } row;                                                             // 57.25 KB
};

// ---- software grid barrier: cheap-coherence version -------------------------
// Arrive: RELEASE fetch_add (one L2 writeback per block). Poll: RELAXED loads
// (no cache ops). Exit: ONE acquire fence (one invalidate per block), then
// __syncthreads publishes to the whole block.
static __device__ __forceinline__ void gridbar(unsigned* bar, unsigned target) {
    __syncthreads();
    if (threadIdx.x == 0) {
        __hip_atomic_fetch_add(bar, 1u, __ATOMIC_RELEASE, __HIP_MEMORY_SCOPE_AGENT);
        while (__hip_atomic_load(bar, __ATOMIC_RELAXED, __HIP_MEMORY_SCOPE_AGENT) < target)
            __builtin_amdgcn_s_sleep(2);
        __builtin_amdgcn_fence(__ATOMIC_ACQUIRE, "agent");
    }
    __syncthreads();
}

// ---------------- P0b: LN(inputs) rows -> bf16, one row per wave ------------
static __device__ void ln_input(const Params& p) {
    const int wid  = (blockIdx.x * 256 + threadIdx.x) >> 6;   // 0..1023
    const int lane = threadIdx.x & 63;
    const float g0 = p.ln_in_g[lane * 4 + 0], g1 = p.ln_in_g[lane * 4 + 1];
    const float g2 = p.ln_in_g[lane * 4 + 2], g3 = p.ln_in_g[lane * 4 + 3];
    const float b0 = p.ln_in_b[lane * 4 + 0], b1 = p.ln_in_b[lane * 4 + 1];
    const float b2 = p.ln_in_b[lane * 4 + 2], b3 = p.ln_in_b[lane * 4 + 3];
    #pragma unroll 2
    for (int row = wid; row < 32768; row += 1024) {
        float4 v = *(const float4*)(p.inputs + (size_t)row * 256 + lane * 4);
        float s  = v.x + v.y + v.z + v.w;
        float ss = v.x * v.x + v.y * v.y + v.z * v.z + v.w * v.w;
        #pragma unroll
        for (int o = 1; o < 64; o <<= 1) { s += __shfl_xor(s, o); ss += __shfl_xor(ss, o); }
        float mean = s * (1.f / 256.f);
        float var  = ss * (1.f / 256.f) - mean * mean;
        float rstd = rsqrtf(var + 1e-5f);
        ushort4 o4;
        o4.x = f2bf((v.x - mean) * rstd * g0 + b0);
        o4.y = f2bf((v.y - mean) * rstd * g1 + b1);
        o4.z = f2bf((v.z - mean) * rstd * g2 + b2);
        o4.w = f2bf((v.w - mean) * rstd * g3 + b3);
        *(ushort4*)(p.x_bf + (size_t)row * 256 + lane * 4) = o4;
    }
}

// ---------------- P1a: kv = x_ln @ [Wk;Wv]^T, one 128x128 tile --------------
static __device__ void kv_tile(const Params& p, Smem& sm, int tile) {
    const int m0 = (tile >> 2) * 128, n0 = (tile & 3) * 128;
    const int t = threadIdx.x, wave = t >> 6, lane = t & 63;
    const int qr = (wave >> 1) * 64, qc = (wave & 1) * 64;
    const int lr = lane & 15, lq = lane >> 4;
    f32x4 acc[4][4] = {};
    const int sr = t >> 2, sl = t & 3, gk = sl * 8;
    const int wsl0 = (sl ^ ((sr >> 1) & 3)) * 8;               // swizzled slots
    const int wsl1 = (sl ^ (((sr + 64) >> 1) & 3)) * 8;
    for (int k0 = 0; k0 < 256; k0 += 32) {
        __syncthreads();
        uint4 a0 = *(const uint4*)(p.x_bf   + (size_t)(m0 + sr)      * 256 + k0 + gk);
        uint4 a1 = *(const uint4*)(p.x_bf   + (size_t)(m0 + sr + 64) * 256 + k0 + gk);
        uint4 b0 = *(const uint4*)(p.kvW_bf + (size_t)(n0 + sr)      * 256 + k0 + gk);
        uint4 b1 = *(const uint4*)(p.kvW_bf + (size_t)(n0 + sr + 64) * 256 + k0 + gk);
        *(uint4*)(sm.g.As + sr * 32 + wsl0) = a0;
        *(uint4*)(sm.g.As + (sr + 64) * 32 + wsl1) = a1;
        *(uint4*)(sm.g.Bs + sr * 32 + wsl0) = b0;
        *(uint4*)(sm.g.Bs + (sr + 64) * 32 + wsl1) = b1;
        __syncthreads();
        bf16x8 af[4], bv[4];
        #pragma unroll
        for (int i = 0; i < 4; i++) {
            const int ra = qr + i * 16 + lr;
            af[i] = *(const bf16x8*)(sm.g.As + ra * 32 + ((lq ^ ((ra >> 1) & 3)) * 8));
        }
        #pragma unroll
        for (int i = 0; i < 4; i++) {
            const int rb = qc + i * 16 + lr;
            bv[i] = *(const bf16x8*)(sm.g.Bs + rb * 32 + ((lq ^ ((rb >> 1) & 3)) * 8));
        }
        #pragma unroll
        for (int i = 0; i < 4; i++)
            #pragma unroll
            for (int j = 0; j < 4; j++)
                acc[i][j] = MFMA16(af[i], bv[j], acc[i][j]);
    }
    #pragma unroll
    for (int i = 0; i < 4; i++)
        #pragma unroll
        for (int j = 0; j < 4; j++) {
            const int col = n0 + qc + j * 16 + lr;
            #pragma unroll
            for (int r = 0; r < 4; r++) {
                const int rw = m0 + qr + i * 16 + lq * 4 + r;
                p.kv[(size_t)rw * 512 + col] = acc[i][j][r];
            }
        }
}

// ---------------- q = ln_s(16 rows in sm.row.u) @ Wq^T ----------------------
static __device__ void qgemm(const Params& p, Smem& sm, int r0) {
    const int t = threadIdx.x, w = t >> 6, lane = t & 63;
    const int lr = lane & 15, lq = lane >> 4;
    f32x4 acc[4] = {};
    for (int k0 = 0; k0 < 256; k0 += 32) {
        bf16x8 a = *(const bf16x8*)&sm.row.u[lr][k0 + lq * 8];
        #pragma unroll
        for (int j = 0; j < 4; ++j) {
            bf16x8 bv = *(const bf16x8*)(p.Wq_bf + (size_t)(w * 64 + j * 16 + lr) * 256 + k0 + lq * 8);
            acc[j] = MFMA16(a, bv, acc[j]);
        }
    }
    #pragma unroll
    for (int j = 0; j < 4; ++j)
        #pragma unroll
        for (int r = 0; r < 4; ++r)
            p.q[(size_t)(r0 + lq * 4 + r) * 256 + w * 64 + j * 16 + lr] = acc[j][r];
}

// ---------------- P1b: initial LN(slots) -> q (blocks 0..15) ----------------
static __device__ void init_q(const Params& p, Smem& sm, int bid) {
    const int t = threadIdx.x;
    const int r0 = bid * 16;
    const int row16 = t >> 4, sub = t & 15;
    float vals[16]; float s = 0.f, ss = 0.f;
    #pragma unroll
    for (int k = 0; k < 16; k += 4) {
        float4 v = *(const float4*)(p.slots + (size_t)(r0 + row16) * 256 + sub * 16 + k);
        vals[k] = v.x; vals[k + 1] = v.y; vals[k + 2] = v.z; vals[k + 3] = v.w;
        s += v.x + v.y + v.z + v.w;
        ss += v.x * v.x + v.y * v.y + v.z * v.z + v.w * v.w;
    }
    #pragma unroll
    for (int m = 1; m < 16; m <<= 1) { s += __shfl_xor(s, m); ss += __shfl_xor(ss, m); }
    const float mean = s * (1.f / 256.f);
    const float var  = ss * (1.f / 256.f) - mean * mean;
    const float rstd = rsqrtf(var + 1e-5f);
    #pragma unroll
    for (int k = 0; k < 16; ++k) {
        const int c = sub * 16 + k;
        sm.row.u[row16][c] = f2bf((vals[k] - mean) * rstd * p.ln_s_g[c] + p.ln_s_b[c]);
    }
    __syncthreads();
    qgemm(p, sm, r0);
}

// ---------------- ATTN: dots + softmax(slots) + EPS + partial sums ----------
// 256 blocks: b = bid>>3 (32 batches), chunk = bid&7 (8 chunks of 128 tokens).
static __device__ void attn_phase(const Params& p, Smem& sm, int bid) {
    const int t = threadIdx.x;
    const int b = bid >> 3, chunk = bid & 7, j0 = chunk * 128;
    {   // q rows for this batch (8 x 256 f32)
        const int i = t >> 5, c0 = (t & 31) * 8;
        const float* qr = p.q + (size_t)(b * 8 + i) * 256 + c0;
        *(float4*)&sm.at.q[i][c0]     = *(const float4*)(qr);
        *(float4*)&sm.at.q[i][c0 + 4] = *(const float4*)(qr + 4);
    }
    __syncthreads();
    {   // dots for 128 tokens x 8 slots
        const int i = t & 7, jj = t >> 3;
        const float4* qrow = (const float4*)&sm.at.q[i][0];
        #pragma unroll 1
        for (int g = 0; g < 4; ++g) {
            const int jl = g * 32 + jj;
            const float4* krow = (const float4*)(p.kv + ((size_t)b * 1024 + j0 + jl) * 512);
            float a0 = 0, a1 = 0, a2 = 0, a3 = 0;
            #pragma unroll 8
            for (int dd = 0; dd < 64; ++dd) {
                float4 qv = qrow[dd], kk = krow[dd];
                a0 += qv.x * kk.x; a1 += qv.y * kk.y; a2 += qv.z * kk.z; a3 += qv.w * kk.w;
            }
            sm.at.sc[i][jl] = (a0 + a1 + a2 + a3) * 0.0625f;   // SCALE
        }
    }
    __syncthreads();
    if (t < 128) {  // softmax over slots per token + EPS
        float v[8], m = -1e30f;
        #pragma unroll
        for (int ii = 0; ii < 8; ++ii) { v[ii] = sm.at.sc[ii][t]; m = fmaxf(m, v[ii]); }
        float s = 0.f;
        #pragma unroll
        for (int ii = 0; ii < 8; ++ii) { v[ii] = __expf(v[ii] - m); s += v[ii]; }
        const float inv = 1.f / s;
        #pragma unroll
        for (int ii = 0; ii < 8; ++ii) sm.at.sc[ii][t] = v[ii] * inv + 1e-8f;
    }
    __syncthreads();
    if (t < 8) {    // per-slot row-sum partial
        float s = 0.f;
        for (int jl = 0; jl < 128; ++jl) s += sm.at.sc[t][jl];
        p.rspart[((size_t)b * 8 + chunk) * 8 + t] = s;
    }
    {   // partial updates: acc[i] += w[i][j] * v[j][d], d = t
        float acc[8] = {};
        const float* vbase = p.kv + ((size_t)b * 1024 + j0) * 512 + 256 + t;
        #pragma unroll 4
        for (int jl = 0; jl < 128; ++jl) {
            const float vv = vbase[(size_t)jl * 512];
            #pragma unroll
            for (int ii = 0; ii < 8; ++ii) acc[ii] += sm.at.sc[ii][jl] * vv;
        }
        float* up = p.upart + (((size_t)b * 8 + chunk) * 8) * 256 + t;
        #pragma unroll
        for (int ii = 0; ii < 8; ++ii) up[(size_t)ii * 256] = acc[ii];
    }
}

// ---------------- ROW: combine -> gates -> GRU -> LN -> MLP -> out -> q -----
static __device__ void row_phase(const Params& p, Smem& sm, int bid, int it) {
    const int t = threadIdx.x;
    const int r0 = bid * 16;
    const int lane = t & 63, w = t >> 6;
    const int lr = lane & 15, lq = lane >> 4;
    const int row16 = t >> 4, sub = t & 15;
    const int c0 = w * 64;

    // 1. slots f32 -> s LDS (+ bf16 h LDS); combine upart/rspart -> u LDS bf16
    #pragma unroll
    for (int k = 0; k < 16; k += 4) {
        float4 v = *(const float4*)(p.slots + (size_t)(r0 + row16) * 256 + sub * 16 + k);
        *(float4*)&sm.row.s[row16][sub * 16 + k] = v;
        sm.row.h[row16][sub * 16 + k]     = f2bf(v.x);
        sm.row.h[row16][sub * 16 + k + 1] = f2bf(v.y);
        sm.row.h[row16][sub * 16 + k + 2] = f2bf(v.z);
        sm.row.h[row16][sub * 16 + k + 3] = f2bf(v.w);
    }
    {
        const int grow = r0 + row16, bb = grow >> 3, ii = grow & 7;
        float rs = 0.f;
        #pragma unroll
        for (int c = 0; c < 8; ++c) rs += p.rspart[((size_t)bb * 8 + c) * 8 + ii];
        const float inv = 1.f / rs;
        float uac[16] = {};
        #pragma unroll
        for (int c = 0; c < 8; ++c) {
            const float* up = p.upart + (((size_t)bb * 8 + c) * 8 + ii) * 256 + sub * 16;
            #pragma unroll
            for (int k = 0; k < 16; k += 4) {
                float4 v = *(const float4*)(up + k);
                uac[k] += v.x; uac[k + 1] += v.y; uac[k + 2] += v.z; uac[k + 3] += v.w;
            }
        }
        #pragma unroll
        for (int k = 0; k < 16; ++k) sm.row.u[row16][sub * 16 + k] = f2bf(uac[k] * inv);
    }
    __syncthreads();

    // 2. GRU gates: wave w owns output cols c0..c0+63; computes gi/gh for all
    //    three col-thirds so the GRU is lane-local (C-layout tiles j, j+16, j+32).
    f32x4 gi[3][4] = {}, gh[3][4] = {};
    for (int k0 = 0; k0 < 256; k0 += 32) {
        bf16x8 au = *(const bf16x8*)&sm.row.u[lr][k0 + lq * 8];
        bf16x8 ah = *(const bf16x8*)&sm.row.h[lr][k0 + lq * 8];
        #pragma unroll
        for (int tau = 0; tau < 3; ++tau)
            #pragma unroll
            for (int j = 0; j < 4; ++j) {
                const size_t boff = (size_t)(tau * 256 + c0 + j * 16 + lr) * 256 + k0 + lq * 8;
                gi[tau][j] = MFMA16(au, *(const bf16x8*)(p.wih_bf + boff), gi[tau][j]);
                gh[tau][j] = MFMA16(ah, *(const bf16x8*)(p.whh_bf + boff), gh[tau][j]);
            }
    }

    // 3. GRU elementwise (lane-local), overwrite s with slots_mid
    #pragma unroll
    for (int j = 0; j < 4; ++j) {
        const int c = c0 + j * 16 + lr;
        const float bir = p.bih[c], biz = p.bih[256 + c], bin_ = p.bih[512 + c];
        const float bhr = p.bhh[c], bhz = p.bhh[256 + c], bhn  = p.bhh[512 + c];
        #pragma unroll
        for (int r = 0; r < 4; ++r) {
            const int rw = lq * 4 + r;
            const float rg = 1.f / (1.f + __expf(-(gi[0][j][r] + bir + gh[0][j][r] + bhr)));
            const float z  = 1.f / (1.f + __expf(-(gi[1][j][r] + biz + gh[1][j][r] + bhz)));
            const float nn = tanhf(gi[2][j][r] + bin_ + rg * (gh[2][j][r] + bhn));
            const float h  = sm.row.s[rw][c];
            sm.row.s[rw][c] = (1.f - z) * nn + z * h;
        }
    }
    __syncthreads();

    // 4. LN_ff -> ff LDS bf16
    {
        float vals[16]; float s_ = 0.f, ss = 0.f;
        #pragma unroll
        for (int k = 0; k < 16; ++k) {
            const float v = sm.row.s[row16][sub * 16 + k];
            vals[k] = v; s_ += v; ss += v * v;
        }
        #pragma unroll
        for (int m = 1; m < 16; m <<= 1) { s_ += __shfl_xor(s_, m); ss += __shfl_xor(ss, m); }
        const float mean = s_ * (1.f / 256.f);
        const float var  = ss * (1.f / 256.f) - mean * mean;
        const float rstd = rsqrtf(var + 1e-5f);
        #pragma unroll
        for (int k = 0; k < 16; ++k) {
            const int c = sub * 16 + k;
            sm.row.ff[row16][c] = f2bf((vals[k] - mean) * rstd * p.ln_ff_g[c] + p.ln_ff_b[c]);
        }
    }
    __syncthreads();

    // 5. MLP: h1 = relu(ff @ w1^T + b1) in 2 halves; out-acc += h1 @ w2^T slice
    f32x4 oacc[4] = {};
    #pragma unroll 1
    for (int half = 0; half < 2; ++half) {
        f32x4 hacc[8] = {};
        for (int k0 = 0; k0 < 256; k0 += 32) {
            bf16x8 af = *(const bf16x8*)&sm.row.ff[lr][k0 + lq * 8];
            #pragma unroll
            for (int j = 0; j < 8; ++j) {
                bf16x8 bv = *(const bf16x8*)(p.w1_bf + (size_t)(half * 512 + w * 128 + j * 16 + lr) * 256 + k0 + lq * 8);
                hacc[j] = MFMA16(af, bv, hacc[j]);
            }
        }
        #pragma unroll
        for (int j = 0; j < 8; ++j) {
            const int cl = w * 128 + j * 16 + lr;
            const float bb = p.b1[half * 512 + cl];
            #pragma unroll
            for (int r = 0; r < 4; ++r)
                sm.row.h1[lq * 4 + r][cl] = f2bf(fmaxf(hacc[j][r] + bb, 0.f));
        }
        __syncthreads();
        for (int k0 = 0; k0 < 512; k0 += 32) {
            bf16x8 a1 = *(const bf16x8*)&sm.row.h1[lr][k0 + lq * 8];
            #pragma unroll
            for (int j = 0; j < 4; ++j) {
                bf16x8 bv = *(const bf16x8*)(p.w2_bf + (size_t)(c0 + j * 16 + lr) * 1024 + half * 512 + k0 + lq * 8);
                oacc[j] = MFMA16(a1, bv, oacc[j]);
            }
        }
        __syncthreads();
    }

    // 6. out = mlp + b2 + slots_mid; write slots (and d_out on last iter)
    const bool last = (it == 2);
    #pragma unroll
    for (int j = 0; j < 4; ++j) {
        const int c = c0 + j * 16 + lr;
        const float bb = p.b2[c];
        #pragma unroll
        for (int r = 0; r < 4; ++r) {
            const int rw = lq * 4 + r;
            const float val = oacc[j][r] + bb + sm.row.s[rw][c];
            sm.row.s[rw][c] = val;
            p.slots[(size_t)(r0 + rw) * 256 + c] = val;
            if (last) p.out[(size_t)(r0 + rw) * 256 + c] = val;
        }
    }
    if (last) return;
    __syncthreads();

    // 7. LN(slots_new) -> u LDS; q for next iteration
    {
        float vals[16]; float s_ = 0.f, ss = 0.f;
        #pragma unroll
        for (int k = 0; k < 16; ++k) {
            const float v = sm.row.s[row16][sub * 16 + k];
            vals[k] = v; s_ += v; ss += v * v;
        }
        #pragma unroll
        for (int m = 1; m < 16; m <<= 1) { s_ += __shfl_xor(s_, m); ss += __shfl_xor(ss, m); }
        const float mean = s_ * (1.f / 256.f);
        const float var  = ss * (1.f / 256.f) - mean * mean;
        const float rstd = rsqrtf(var + 1e-5f);
        #pragma unroll
        for (int k = 0; k < 16; ++k) {
            const int c = sub * 16 + k;
            sm.row.u[row16][c] = f2bf((vals[k] - mean) * rstd * p.ln_s_g[c] + p.ln_s_b[c]);
        }
    }
    __syncthreads();
    qgemm(p, sm, r0);
}

// ---------------------------------------------------------------------------
__global__ __launch_bounds__(256) void fused(Params p) {
    __shared__ Smem sm;
    const int bid = blockIdx.x, t = threadIdx.x;
    unsigned target = 0;

    // ---- P0: weights -> bf16, slots init, LN(inputs) -> bf16
    for (int gid = bid * 256 + t; gid < 1179648; gid += 65536) {
        if      (gid <   65536) p.kvW_bf[gid]          = f2bf(p.Wk[gid]);
        else if (gid <  131072) p.kvW_bf[gid]          = f2bf(p.Wv[gid -   65536]);
        else if (gid <  196608) p.Wq_bf[gid - 131072]  = f2bf(p.Wq[gid -  131072]);
        else if (gid <  393216) p.wih_bf[gid - 196608] = f2bf(p.wih[gid - 196608]);
        else if (gid <  589824) p.whh_bf[gid - 393216] = f2bf(p.whh[gid - 393216]);
        else if (gid <  851968) p.w1_bf[gid - 589824]  = f2bf(p.w1[gid -  589824]);
        else if (gid < 1114112) p.w2_bf[gid - 851968]  = f2bf(p.w2[gid -  851968]);
        else {
            const int i = gid - 1114112;
            const int d = i & 255;
            p.slots[i] = p.mu[d] + expf(p.ls[d]) * p.noise[i];
        }
    }
    ln_input(p);
    gridbar(p.bar, target += 256);

    // ---- P1: kv GEMM (1024 tiles, 4/block) + initial q (blocks 0..15)
    for (int tt = bid; tt < 1024; tt += 256) kv_tile(p, sm, tt);
    if (bid < 16) { __syncthreads(); init_q(p, sm, bid); }
    gridbar(p.bar, target += 256);

    // ---- 3 slot-attention iterations
    for (int it = 0; it < 3; ++it) {
        attn_phase(p, sm, bid);
        gridbar(p.bar, target += 256);
        if (bid < 16) row_phase(p, sm, bid, it);
        if (it < 2) gridbar(p.bar, target += 256);
    }
}

// ---------------------------------------------------------------------------
extern "C" void kernel_launch(void* const* d_in, const int* in_sizes, int n_in,
                              void* d_out, int out_size, void* d_ws, size_t ws_size,
                              hipStream_t stream)
{
    (void)in_sizes; (void)n_in; (void)out_size; (void)ws_size;

    Params prm;
    prm.inputs  = (const float*)d_in[0];
    prm.noise   = (const float*)d_in[1];
    prm.mu      = (const float*)d_in[2];
    prm.ls      = (const float*)d_in[3];
    prm.Wq      = (const float*)d_in[4];
    prm.Wk      = (const float*)d_in[5];
    prm.Wv      = (const float*)d_in[6];
    prm.wih     = (const float*)d_in[7];
    prm.whh     = (const float*)d_in[8];
    prm.bih     = (const float*)d_in[9];
    prm.bhh     = (const float*)d_in[10];
    prm.w1      = (const float*)d_in[11];
    prm.b1      = (const float*)d_in[12];
    prm.w2      = (const float*)d_in[13];
    prm.b2      = (const float*)d_in[14];
    prm.ln_in_g = (const float*)d_in[15];
    prm.ln_in_b = (const float*)d_in[16];
    prm.ln_s_g  = (const float*)d_in[17];
    prm.ln_s_b  = (const float*)d_in[18];
    prm.ln_ff_g = (const float*)d_in[19];
    prm.ln_ff_b = (const float*)d_in[20];
    prm.out     = (float*)d_out;

    char* ptr = (char*)d_ws;
    auto alloc = [&](size_t bytes) -> char* {
        char* r = ptr; ptr += (bytes + 255) & ~(size_t)255; return r;
    };
    prm.bar    = (unsigned*)      alloc(256);
    prm.x_bf   = (unsigned short*)alloc((size_t)32768 * 256 * 2);
    prm.kv     = (float*)         alloc((size_t)32768 * 512 * 4);
    prm.kvW_bf = (unsigned short*)alloc(512 * 256 * 2);
    prm.Wq_bf  = (unsigned short*)alloc(256 * 256 * 2);
    prm.wih_bf = (unsigned short*)alloc(768 * 256 * 2);
    prm.whh_bf = (unsigned short*)alloc(768 * 256 * 2);
    prm.w1_bf  = (unsigned short*)alloc(1024 * 256 * 2);
    prm.w2_bf  = (unsigned short*)alloc(256 * 1024 * 2);
    prm.slots  = (float*)         alloc(256 * 256 * 4);
    prm.q      = (float*)         alloc(256 * 256 * 4);
    prm.upart  = (float*)         alloc((size_t)32 * 8 * 8 * 256 * 4);
    prm.rspart = (float*)         alloc(32 * 8 * 8 * 4);

    hipMemsetAsync(prm.bar, 0, 256, stream);
    fused<<<dim3(256), dim3(256), 0, stream>>>(prm);
}

// Round 4
// 690.597 us; speedup vs baseline: 3.1689x; 1.0908x over previous
//
#include <hip/hip_runtime.h>

// ---------------------------------------------------------------------------
// SlotAttention on MI355X (gfx950) — single persistent kernel, software grid
// barrier. 256 blocks x 256 threads: 1 block/CU -> spin barrier deadlock-proof.
// Round-2 lesson: ACQUIRE polling at agent scope = cache ops per poll (~300us/bar).
// Round-3 lesson: even RELAXED polls of ONE line serialize at the coherence
// point (per-XCD L2s non-coherent -> agent atomics go memory-side): ~70us/bar.
// Fix: hierarchical barrier — 8 per-group arrival counters (own 256B lines),
// leaders -> 1 global counter, master publishes 8 per-group release words;
// pollers spin on their group word with s_sleep(16). One acquire fence per
// block per barrier (cross-XCD visibility of q/upart/slots), once, on exit.
// Phases (7 barriers):
//   P0: weight->bf16 + slots init + LN(inputs)->bf16
//   P1: kv GEMM (1024 tiles, 4/block) + init q (blocks 0..15)
//   3x { ATTN (256 blocks: 32 b x 8 chunks of 128 tokens) ; ROW (16 blocks,
//        16 slot-rows each: combine+GRU+LN+MLP+residual+LN+next-q) }
// MFMA fragment layouts per learn_hip m89/m97 (ref-verified):
//   A/B operand: idx = lane&15 (m or n), k = (lane>>4)*8 + j
//   C/D:         col = lane&15, row = (lane>>4)*4 + reg
// kv-GEMM LDS tiles XOR-swizzled (slot ^= (row>>1)&3): read conflicts 8->2 way.
// ---------------------------------------------------------------------------

typedef __attribute__((ext_vector_type(8))) __bf16 bf16x8;
typedef __attribute__((ext_vector_type(4))) float  f32x4;

#define MFMA16(a, b, c) __builtin_amdgcn_mfma_f32_16x16x32_bf16((a), (b), (c), 0, 0, 0)

static __device__ __forceinline__ unsigned short f2bf(float f) {
    unsigned int x = __float_as_uint(f);
    x = (x + 0x7fffu + ((x >> 16) & 1u)) >> 16;   // RN-even
    return (unsigned short)x;
}

struct Params {
    const float *inputs, *noise, *mu, *ls;
    const float *Wq, *Wk, *Wv, *wih, *whh, *bih, *bhh, *w1, *b1, *w2, *b2;
    const float *ln_in_g, *ln_in_b, *ln_s_g, *ln_s_b, *ln_ff_g, *ln_ff_b;
    float* out;
    unsigned*  bar;   // barrier lines (memset to 0 before launch), 64-uint stride
    unsigned short *x_bf, *kvW_bf, *Wq_bf, *wih_bf, *whh_bf, *w1_bf, *w2_bf;
    float *kv, *slots, *q, *upart, *rspart;
};

union Smem {
    struct { unsigned short As[128 * 32], Bs[128 * 32]; } g;          // 16 KB (kv gemm)
    struct { float q[8][260]; float sc[8][132]; } at;                 // 12.3 KB (attn)
    struct {
        unsigned short u[16][264];     // combine result / ln_s (bf16, pad +8)
        unsigned short h[16][264];     // slots_prev bf16
        unsigned short ff[16][264];    // LN_ff out bf16
        unsigned short h1[16][520];    // half of MLP hidden (512 + 8 pad)
        float          s[16][260];     // slots f32 (prev -> mid -> new)
    } row;                                                             // 57.25 KB
};

// ---- hierarchical software grid barrier ------------------------------------
// bar layout (uints, 64-uint = 256B stride): cnt[g]=bar+g*64 (g=0..7),
// gcnt=bar+8*64, rel[g]=bar+(9+g)*64. Counters monotonic across phases
// (ph = 1..7): group-last sees my == 32*ph-1, global master gm == 8*ph-1.
static __device__ __forceinline__ void gridbar(unsigned* bar, unsigned ph) {
    __syncthreads();
    if (threadIdx.x == 0) {
        const unsigned g = blockIdx.x & 7;
        unsigned my = __hip_atomic_fetch_add(bar + g * 64, 1u,
                                             __ATOMIC_ACQ_REL, __HIP_MEMORY_SCOPE_AGENT);
        if (my == ph * 32u - 1u) {                      // last of my group
            unsigned gm = __hip_atomic_fetch_add(bar + 8 * 64, 1u,
                                                 __ATOMIC_ACQ_REL, __HIP_MEMORY_SCOPE_AGENT);
            if (gm == ph * 8u - 1u) {                   // global master: publish
                #pragma unroll
                for (int k = 0; k < 8; ++k)
                    __hip_atomic_store(bar + (9 + k) * 64, ph,
                                       __ATOMIC_RELEASE, __HIP_MEMORY_SCOPE_AGENT);
            }
        }
        while (__hip_atomic_load(bar + (9 + g) * 64,
                                 __ATOMIC_RELAXED, __HIP_MEMORY_SCOPE_AGENT) < ph)
            __builtin_amdgcn_s_sleep(16);
        __builtin_amdgcn_fence(__ATOMIC_ACQUIRE, "agent");
    }
    __syncthreads();
}

// ---------------- P0b: LN(inputs) rows -> bf16, one row per wave ------------
static __device__ void ln_input(const Params& p) {
    const int wid  = (blockIdx.x * 256 + threadIdx.x) >> 6;   // 0..1023
    const int lane = threadIdx.x & 63;
    const float g0 = p.ln_in_g[lane * 4 + 0], g1 = p.ln_in_g[lane * 4 + 1];
    const float g2 = p.ln_in_g[lane * 4 + 2], g3 = p.ln_in_g[lane * 4 + 3];
    const float b0 = p.ln_in_b[lane * 4 + 0], b1 = p.ln_in_b[lane * 4 + 1];
    const float b2 = p.ln_in_b[lane * 4 + 2], b3 = p.ln_in_b[lane * 4 + 3];
    #pragma unroll 2
    for (int row = wid; row < 32768; row += 1024) {
        float4 v = *(const float4*)(p.inputs + (size_t)row * 256 + lane * 4);
        float s  = v.x + v.y + v.z + v.w;
        float ss = v.x * v.x + v.y * v.y + v.z * v.z + v.w * v.w;
        #pragma unroll
        for (int o = 1; o < 64; o <<= 1) { s += __shfl_xor(s, o); ss += __shfl_xor(ss, o); }
        float mean = s * (1.f / 256.f);
        float var  = ss * (1.f / 256.f) - mean * mean;
        float rstd = rsqrtf(var + 1e-5f);
        ushort4 o4;
        o4.x = f2bf((v.x - mean) * rstd * g0 + b0);
        o4.y = f2bf((v.y - mean) * rstd * g1 + b1);
        o4.z = f2bf((v.z - mean) * rstd * g2 + b2);
        o4.w = f2bf((v.w - mean) * rstd * g3 + b3);
        *(ushort4*)(p.x_bf + (size_t)row * 256 + lane * 4) = o4;
    }
}

// ---------------- P1a: kv = x_ln @ [Wk;Wv]^T, one 128x128 tile --------------
static __device__ void kv_tile(const Params& p, Smem& sm, int tile) {
    const int m0 = (tile >> 2) * 128, n0 = (tile & 3) * 128;
    const int t = threadIdx.x, wave = t >> 6, lane = t & 63;
    const int qr = (wave >> 1) * 64, qc = (wave & 1) * 64;
    const int lr = lane & 15, lq = lane >> 4;
    f32x4 acc[4][4] = {};
    const int sr = t >> 2, sl = t & 3, gk = sl * 8;
    const int wsl0 = (sl ^ ((sr >> 1) & 3)) * 8;               // swizzled slots
    const int wsl1 = (sl ^ (((sr + 64) >> 1) & 3)) * 8;
    for (int k0 = 0; k0 < 256; k0 += 32) {
        __syncthreads();
        uint4 a0 = *(const uint4*)(p.x_bf   + (size_t)(m0 + sr)      * 256 + k0 + gk);
        uint4 a1 = *(const uint4*)(p.x_bf   + (size_t)(m0 + sr + 64) * 256 + k0 + gk);
        uint4 b0 = *(const uint4*)(p.kvW_bf + (size_t)(n0 + sr)      * 256 + k0 + gk);
        uint4 b1 = *(const uint4*)(p.kvW_bf + (size_t)(n0 + sr + 64) * 256 + k0 + gk);
        *(uint4*)(sm.g.As + sr * 32 + wsl0) = a0;
        *(uint4*)(sm.g.As + (sr + 64) * 32 + wsl1) = a1;
        *(uint4*)(sm.g.Bs + sr * 32 + wsl0) = b0;
        *(uint4*)(sm.g.Bs + (sr + 64) * 32 + wsl1) = b1;
        __syncthreads();
        bf16x8 af[4], bv[4];
        #pragma unroll
        for (int i = 0; i < 4; i++) {
            const int ra = qr + i * 16 + lr;
            af[i] = *(const bf16x8*)(sm.g.As + ra * 32 + ((lq ^ ((ra >> 1) & 3)) * 8));
        }
        #pragma unroll
        for (int i = 0; i < 4; i++) {
            const int rb = qc + i * 16 + lr;
            bv[i] = *(const bf16x8*)(sm.g.Bs + rb * 32 + ((lq ^ ((rb >> 1) & 3)) * 8));
        }
        #pragma unroll
        for (int i = 0; i < 4; i++)
            #pragma unroll
            for (int j = 0; j < 4; j++)
                acc[i][j] = MFMA16(af[i], bv[j], acc[i][j]);
    }
    #pragma unroll
    for (int i = 0; i < 4; i++)
        #pragma unroll
        for (int j = 0; j < 4; j++) {
            const int col = n0 + qc + j * 16 + lr;
            #pragma unroll
            for (int r = 0; r < 4; r++) {
                const int rw = m0 + qr + i * 16 + lq * 4 + r;
                p.kv[(size_t)rw * 512 + col] = acc[i][j][r];
            }
        }
}

// ---------------- q = ln_s(16 rows in sm.row.u) @ Wq^T ----------------------
static __device__ void qgemm(const Params& p, Smem& sm, int r0) {
    const int t = threadIdx.x, w = t >> 6, lane = t & 63;
    const int lr = lane & 15, lq = lane >> 4;
    f32x4 acc[4] = {};
    for (int k0 = 0; k0 < 256; k0 += 32) {
        bf16x8 a = *(const bf16x8*)&sm.row.u[lr][k0 + lq * 8];
        #pragma unroll
        for (int j = 0; j < 4; ++j) {
            bf16x8 bv = *(const bf16x8*)(p.Wq_bf + (size_t)(w * 64 + j * 16 + lr) * 256 + k0 + lq * 8);
            acc[j] = MFMA16(a, bv, acc[j]);
        }
    }
    #pragma unroll
    for (int j = 0; j < 4; ++j)
        #pragma unroll
        for (int r = 0; r < 4; ++r)
            p.q[(size_t)(r0 + lq * 4 + r) * 256 + w * 64 + j * 16 + lr] = acc[j][r];
}

// ---------------- P1b: initial LN(slots) -> q (blocks 0..15) ----------------
static __device__ void init_q(const Params& p, Smem& sm, int bid) {
    const int t = threadIdx.x;
    const int r0 = bid * 16;
    const int row16 = t >> 4, sub = t & 15;
    float vals[16]; float s = 0.f, ss = 0.f;
    #pragma unroll
    for (int k = 0; k < 16; k += 4) {
        float4 v = *(const float4*)(p.slots + (size_t)(r0 + row16) * 256 + sub * 16 + k);
        vals[k] = v.x; vals[k + 1] = v.y; vals[k + 2] = v.z; vals[k + 3] = v.w;
        s += v.x + v.y + v.z + v.w;
        ss += v.x * v.x + v.y * v.y + v.z * v.z + v.w * v.w;
    }
    #pragma unroll
    for (int m = 1; m < 16; m <<= 1) { s += __shfl_xor(s, m); ss += __shfl_xor(ss, m); }
    const float mean = s * (1.f / 256.f);
    const float var  = ss * (1.f / 256.f) - mean * mean;
    const float rstd = rsqrtf(var + 1e-5f);
    #pragma unroll
    for (int k = 0; k < 16; ++k) {
        const int c = sub * 16 + k;
        sm.row.u[row16][c] = f2bf((vals[k] - mean) * rstd * p.ln_s_g[c] + p.ln_s_b[c]);
    }
    __syncthreads();
    qgemm(p, sm, r0);
}

// ---------------- ATTN: dots + softmax(slots) + EPS + partial sums ----------
// 256 blocks: b = bid>>3 (32 batches), chunk = bid&7 (8 chunks of 128 tokens).
static __device__ void attn_phase(const Params& p, Smem& sm, int bid) {
    const int t = threadIdx.x;
    const int b = bid >> 3, chunk = bid & 7, j0 = chunk * 128;
    {   // q rows for this batch (8 x 256 f32)
        const int i = t >> 5, c0 = (t & 31) * 8;
        const float* qr = p.q + (size_t)(b * 8 + i) * 256 + c0;
        *(float4*)&sm.at.q[i][c0]     = *(const float4*)(qr);
        *(float4*)&sm.at.q[i][c0 + 4] = *(const float4*)(qr + 4);
    }
    __syncthreads();
    {   // dots for 128 tokens x 8 slots
        const int i = t & 7, jj = t >> 3;
        const float4* qrow = (const float4*)&sm.at.q[i][0];
        #pragma unroll 1
        for (int g = 0; g < 4; ++g) {
            const int jl = g * 32 + jj;
            const float4* krow = (const float4*)(p.kv + ((size_t)b * 1024 + j0 + jl) * 512);
            float a0 = 0, a1 = 0, a2 = 0, a3 = 0;
            #pragma unroll 8
            for (int dd = 0; dd < 64; ++dd) {
                float4 qv = qrow[dd], kk = krow[dd];
                a0 += qv.x * kk.x; a1 += qv.y * kk.y; a2 += qv.z * kk.z; a3 += qv.w * kk.w;
            }
            sm.at.sc[i][jl] = (a0 + a1 + a2 + a3) * 0.0625f;   // SCALE
        }
    }
    __syncthreads();
    if (t < 128) {  // softmax over slots per token + EPS
        float v[8], m = -1e30f;
        #pragma unroll
        for (int ii = 0; ii < 8; ++ii) { v[ii] = sm.at.sc[ii][t]; m = fmaxf(m, v[ii]); }
        float s = 0.f;
        #pragma unroll
        for (int ii = 0; ii < 8; ++ii) { v[ii] = __expf(v[ii] - m); s += v[ii]; }
        const float inv = 1.f / s;
        #pragma unroll
        for (int ii = 0; ii < 8; ++ii) sm.at.sc[ii][t] = v[ii] * inv + 1e-8f;
    }
    __syncthreads();
    if (t < 8) {    // per-slot row-sum partial
        float s = 0.f;
        for (int jl = 0; jl < 128; ++jl) s += sm.at.sc[t][jl];
        p.rspart[((size_t)b * 8 + chunk) * 8 + t] = s;
    }
    {   // partial updates: acc[i] += w[i][j] * v[j][d], d = t
        float acc[8] = {};
        const float* vbase = p.kv + ((size_t)b * 1024 + j0) * 512 + 256 + t;
        #pragma unroll 8
        for (int jl = 0; jl < 128; ++jl) {
            const float vv = vbase[(size_t)jl * 512];
            #pragma unroll
            for (int ii = 0; ii < 8; ++ii) acc[ii] += sm.at.sc[ii][jl] * vv;
        }
        float* up = p.upart + (((size_t)b * 8 + chunk) * 8) * 256 + t;
        #pragma unroll
        for (int ii = 0; ii < 8; ++ii) up[(size_t)ii * 256] = acc[ii];
    }
}

// ---------------- ROW: combine -> gates -> GRU -> LN -> MLP -> out -> q -----
static __device__ void row_phase(const Params& p, Smem& sm, int bid, int it) {
    const int t = threadIdx.x;
    const int r0 = bid * 16;
    const int lane = t & 63, w = t >> 6;
    const int lr = lane & 15, lq = lane >> 4;
    const int row16 = t >> 4, sub = t & 15;
    const int c0 = w * 64;

    // 1. slots f32 -> s LDS (+ bf16 h LDS); combine upart/rspart -> u LDS bf16
    #pragma unroll
    for (int k = 0; k < 16; k += 4) {
        float4 v = *(const float4*)(p.slots + (size_t)(r0 + row16) * 256 + sub * 16 + k);
        *(float4*)&sm.row.s[row16][sub * 16 + k] = v;
        sm.row.h[row16][sub * 16 + k]     = f2bf(v.x);
        sm.row.h[row16][sub * 16 + k + 1] = f2bf(v.y);
        sm.row.h[row16][sub * 16 + k + 2] = f2bf(v.z);
        sm.row.h[row16][sub * 16 + k + 3] = f2bf(v.w);
    }
    {
        const int grow = r0 + row16, bb = grow >> 3, ii = grow & 7;
        float rs = 0.f;
        #pragma unroll
        for (int c = 0; c < 8; ++c) rs += p.rspart[((size_t)bb * 8 + c) * 8 + ii];
        const float inv = 1.f / rs;
        float uac[16] = {};
        #pragma unroll
        for (int c = 0; c < 8; ++c) {
            const float* up = p.upart + (((size_t)bb * 8 + c) * 8 + ii) * 256 + sub * 16;
            #pragma unroll
            for (int k = 0; k < 16; k += 4) {
                float4 v = *(const float4*)(up + k);
                uac[k] += v.x; uac[k + 1] += v.y; uac[k + 2] += v.z; uac[k + 3] += v.w;
            }
        }
        #pragma unroll
        for (int k = 0; k < 16; ++k) sm.row.u[row16][sub * 16 + k] = f2bf(uac[k] * inv);
    }
    __syncthreads();

    // 2. GRU gates: wave w owns output cols c0..c0+63; computes gi/gh for all
    //    three col-thirds so the GRU is lane-local (C-layout tiles j, j+16, j+32).
    f32x4 gi[3][4] = {}, gh[3][4] = {};
    for (int k0 = 0; k0 < 256; k0 += 32) {
        bf16x8 au = *(const bf16x8*)&sm.row.u[lr][k0 + lq * 8];
        bf16x8 ah = *(const bf16x8*)&sm.row.h[lr][k0 + lq * 8];
        #pragma unroll
        for (int tau = 0; tau < 3; ++tau)
            #pragma unroll
            for (int j = 0; j < 4; ++j) {
                const size_t boff = (size_t)(tau * 256 + c0 + j * 16 + lr) * 256 + k0 + lq * 8;
                gi[tau][j] = MFMA16(au, *(const bf16x8*)(p.wih_bf + boff), gi[tau][j]);
                gh[tau][j] = MFMA16(ah, *(const bf16x8*)(p.whh_bf + boff), gh[tau][j]);
            }
    }

    // 3. GRU elementwise (lane-local), overwrite s with slots_mid
    #pragma unroll
    for (int j = 0; j < 4; ++j) {
        const int c = c0 + j * 16 + lr;
        const float bir = p.bih[c], biz = p.bih[256 + c], bin_ = p.bih[512 + c];
        const float bhr = p.bhh[c], bhz = p.bhh[256 + c], bhn  = p.bhh[512 + c];
        #pragma unroll
        for (int r = 0; r < 4; ++r) {
            const int rw = lq * 4 + r;
            const float rg = 1.f / (1.f + __expf(-(gi[0][j][r] + bir + gh[0][j][r] + bhr)));
            const float z  = 1.f / (1.f + __expf(-(gi[1][j][r] + biz + gh[1][j][r] + bhz)));
            const float nn = tanhf(gi[2][j][r] + bin_ + rg * (gh[2][j][r] + bhn));
            const float h  = sm.row.s[rw][c];
            sm.row.s[rw][c] = (1.f - z) * nn + z * h;
        }
    }
    __syncthreads();

    // 4. LN_ff -> ff LDS bf16
    {
        float vals[16]; float s_ = 0.f, ss = 0.f;
        #pragma unroll
        for (int k = 0; k < 16; ++k) {
            const float v = sm.row.s[row16][sub * 16 + k];
            vals[k] = v; s_ += v; ss += v * v;
        }
        #pragma unroll
        for (int m = 1; m < 16; m <<= 1) { s_ += __shfl_xor(s_, m); ss += __shfl_xor(ss, m); }
        const float mean = s_ * (1.f / 256.f);
        const float var  = ss * (1.f / 256.f) - mean * mean;
        const float rstd = rsqrtf(var + 1e-5f);
        #pragma unroll
        for (int k = 0; k < 16; ++k) {
            const int c = sub * 16 + k;
            sm.row.ff[row16][c] = f2bf((vals[k] - mean) * rstd * p.ln_ff_g[c] + p.ln_ff_b[c]);
        }
    }
    __syncthreads();

    // 5. MLP: h1 = relu(ff @ w1^T + b1) in 2 halves; out-acc += h1 @ w2^T slice
    f32x4 oacc[4] = {};
    #pragma unroll 1
    for (int half = 0; half < 2; ++half) {
        f32x4 hacc[8] = {};
        for (int k0 = 0; k0 < 256; k0 += 32) {
            bf16x8 af = *(const bf16x8*)&sm.row.ff[lr][k0 + lq * 8];
            #pragma unroll
            for (int j = 0; j < 8; ++j) {
                bf16x8 bv = *(const bf16x8*)(p.w1_bf + (size_t)(half * 512 + w * 128 + j * 16 + lr) * 256 + k0 + lq * 8);
                hacc[j] = MFMA16(af, bv, hacc[j]);
            }
        }
        #pragma unroll
        for (int j = 0; j < 8; ++j) {
            const int cl = w * 128 + j * 16 + lr;
            const float bb = p.b1[half * 512 + cl];
            #pragma unroll
            for (int r = 0; r < 4; ++r)
                sm.row.h1[lq * 4 + r][cl] = f2bf(fmaxf(hacc[j][r] + bb, 0.f));
        }
        __syncthreads();
        for (int k0 = 0; k0 < 512; k0 += 32) {
            bf16x8 a1 = *(const bf16x8*)&sm.row.h1[lr][k0 + lq * 8];
            #pragma unroll
            for (int j = 0; j < 4; ++j) {
                bf16x8 bv = *(const bf16x8*)(p.w2_bf + (size_t)(c0 + j * 16 + lr) * 1024 + half * 512 + k0 + lq * 8);
                oacc[j] = MFMA16(a1, bv, oacc[j]);
            }
        }
        __syncthreads();
    }

    // 6. out = mlp + b2 + slots_mid; write slots (and d_out on last iter)
    const bool last = (it == 2);
    #pragma unroll
    for (int j = 0; j < 4; ++j) {
        const int c = c0 + j * 16 + lr;
        const float bb = p.b2[c];
        #pragma unroll
        for (int r = 0; r < 4; ++r) {
            const int rw = lq * 4 + r;
            const float val = oacc[j][r] + bb + sm.row.s[rw][c];
            sm.row.s[rw][c] = val;
            p.slots[(size_t)(r0 + rw) * 256 + c] = val;
            if (last) p.out[(size_t)(r0 + rw) * 256 + c] = val;
        }
    }
    if (last) return;
    __syncthreads();

    // 7. LN(slots_new) -> u LDS; q for next iteration
    {
        float vals[16]; float s_ = 0.f, ss = 0.f;
        #pragma unroll
        for (int k = 0; k < 16; ++k) {
            const float v = sm.row.s[row16][sub * 16 + k];
            vals[k] = v; s_ += v; ss += v * v;
        }
        #pragma unroll
        for (int m = 1; m < 16; m <<= 1) { s_ += __shfl_xor(s_, m); ss += __shfl_xor(ss, m); }
        const float mean = s_ * (1.f / 256.f);
        const float var  = ss * (1.f / 256.f) - mean * mean;
        const float rstd = rsqrtf(var + 1e-5f);
        #pragma unroll
        for (int k = 0; k < 16; ++k) {
            const int c = sub * 16 + k;
            sm.row.u[row16][c] = f2bf((vals[k] - mean) * rstd * p.ln_s_g[c] + p.ln_s_b[c]);
        }
    }
    __syncthreads();
    qgemm(p, sm, r0);
}

// ---------------------------------------------------------------------------
__global__ __launch_bounds__(256) void fused(Params p) {
    __shared__ Smem sm;
    const int bid = blockIdx.x, t = threadIdx.x;
    unsigned ph = 0;

    // ---- P0: weights -> bf16, slots init, LN(inputs) -> bf16
    for (int gid = bid * 256 + t; gid < 1179648; gid += 65536) {
        if      (gid <   65536) p.kvW_bf[gid]          = f2bf(p.Wk[gid]);
        else if (gid <  131072) p.kvW_bf[gid]          = f2bf(p.Wv[gid -   65536]);
        else if (gid <  196608) p.Wq_bf[gid - 131072]  = f2bf(p.Wq[gid -  131072]);
        else if (gid <  393216) p.wih_bf[gid - 196608] = f2bf(p.wih[gid - 196608]);
        else if (gid <  589824) p.whh_bf[gid - 393216] = f2bf(p.whh[gid - 393216]);
        else if (gid <  851968) p.w1_bf[gid - 589824]  = f2bf(p.w1[gid -  589824]);
        else if (gid < 1114112) p.w2_bf[gid - 851968]  = f2bf(p.w2[gid -  851968]);
        else {
            const int i = gid - 1114112;
            const int d = i & 255;
            p.slots[i] = p.mu[d] + expf(p.ls[d]) * p.noise[i];
        }
    }
    ln_input(p);
    gridbar(p.bar, ++ph);

    // ---- P1: kv GEMM (1024 tiles, 4/block) + initial q (blocks 0..15)
    for (int tt = bid; tt < 1024; tt += 256) kv_tile(p, sm, tt);
    if (bid < 16) { __syncthreads(); init_q(p, sm, bid); }
    gridbar(p.bar, ++ph);

    // ---- 3 slot-attention iterations
    for (int it = 0; it < 3; ++it) {
        attn_phase(p, sm, bid);
        gridbar(p.bar, ++ph);
        if (bid < 16) row_phase(p, sm, bid, it);
        if (it < 2) gridbar(p.bar, ++ph);
    }
}

// ---------------------------------------------------------------------------
extern "C" void kernel_launch(void* const* d_in, const int* in_sizes, int n_in,
                              void* d_out, int out_size, void* d_ws, size_t ws_size,
                              hipStream_t stream)
{
    (void)in_sizes; (void)n_in; (void)out_size; (void)ws_size;

    Params prm;
    prm.inputs  = (const float*)d_in[0];
    prm.noise   = (const float*)d_in[1];
    prm.mu      = (const float*)d_in[2];
    prm.ls      = (const float*)d_in[3];
    prm.Wq      = (const float*)d_in[4];
    prm.Wk      = (const float*)d_in[5];
    prm.Wv      = (const float*)d_in[6];
    prm.wih     = (const float*)d_in[7];
    prm.whh     = (const float*)d_in[8];
    prm.bih     = (const float*)d_in[9];
    prm.bhh     = (const float*)d_in[10];
    prm.w1      = (const float*)d_in[11];
    prm.b1      = (const float*)d_in[12];
    prm.w2      = (const float*)d_in[13];
    prm.b2      = (const float*)d_in[14];
    prm.ln_in_g = (const float*)d_in[15];
    prm.ln_in_b = (const float*)d_in[16];
    prm.ln_s_g  = (const float*)d_in[17];
    prm.ln_s_b  = (const float*)d_in[18];
    prm.ln_ff_g = (const float*)d_in[19];
    prm.ln_ff_b = (const float*)d_in[20];
    prm.out     = (float*)d_out;

    char* ptr = (char*)d_ws;
    auto alloc = [&](size_t bytes) -> char* {
        char* r = ptr; ptr += (bytes + 255) & ~(size_t)255; return r;
    };
    prm.bar    = (unsigned*)      alloc(8192);
    prm.x_bf   = (unsigned short*)alloc((size_t)32768 * 256 * 2);
    prm.kv     = (float*)         alloc((size_t)32768 * 512 * 4);
    prm.kvW_bf = (unsigned short*)alloc(512 * 256 * 2);
    prm.Wq_bf  = (unsigned short*)alloc(256 * 256 * 2);
    prm.wih_bf = (unsigned short*)alloc(768 * 256 * 2);
    prm.whh_bf = (unsigned short*)alloc(768 * 256 * 2);
    prm.w1_bf  = (unsigned short*)alloc(1024 * 256 * 2);
    prm.w2_bf  = (unsigned short*)alloc(256 * 1024 * 2);
    prm.slots  = (float*)         alloc(256 * 256 * 4);
    prm.q      = (float*)         alloc(256 * 256 * 4);
    prm.upart  = (float*)         alloc((size_t)32 * 8 * 8 * 256 * 4);
    prm.rspart = (float*)         alloc(32 * 8 * 8 * 4);

    hipMemsetAsync(prm.bar, 0, 8192, stream);
    fused<<<dim3(256), dim3(256), 0, stream>>>(prm);
}